// Round 5
// baseline (1184.739 us; speedup 1.0000x reference)
//
#include <hip/hip_runtime.h>
#include <stdint.h>

// Problem constants
#define BATCH 4096
#define DIMD  256
#define DIMH  1024
#define EPAD  264   // E tile row stride in bf16 elems (256 + 8 pad; measured ~0.25 cyc/read conflict cost)

typedef __attribute__((ext_vector_type(8))) short short8;
typedef __attribute__((ext_vector_type(4))) float float4v;

// ---------------- threefry2x32 (JAX-compatible, 20 rounds) ----------------
__host__ __device__ static inline uint32_t rotl32(uint32_t v, int r) {
    return (v << r) | (v >> (32 - r));
}

__host__ __device__ static inline void tf2x32(uint32_t k0, uint32_t k1,
                                              uint32_t c0, uint32_t c1,
                                              uint32_t& o0, uint32_t& o1) {
    uint32_t ks0 = k0, ks1 = k1, ks2 = k0 ^ k1 ^ 0x1BD11BDAu;
    uint32_t x0 = c0 + ks0, x1 = c1 + ks1;
#define TF_R4(a, b, c, d)                                   \
    x0 += x1; x1 = rotl32(x1, a); x1 ^= x0;                 \
    x0 += x1; x1 = rotl32(x1, b); x1 ^= x0;                 \
    x0 += x1; x1 = rotl32(x1, c); x1 ^= x0;                 \
    x0 += x1; x1 = rotl32(x1, d); x1 ^= x0;
    TF_R4(13, 15, 26, 6)  x0 += ks1; x1 += ks2 + 1u;
    TF_R4(17, 29, 16, 24) x0 += ks2; x1 += ks0 + 2u;
    TF_R4(13, 15, 26, 6)  x0 += ks0; x1 += ks1 + 3u;
    TF_R4(17, 29, 16, 24) x0 += ks1; x1 += ks2 + 4u;
    TF_R4(13, 15, 26, 6)  x0 += ks2; x1 += ks0 + 5u;
#undef TF_R4
    o0 = x0; o1 = x1;
}

// float -> bf16 (round-to-nearest-even), bit pattern in a short
__device__ static inline short f2bf(float f) {
    uint32_t u = __float_as_uint(f);
    uint32_t r = (u + 0x7FFFu + ((u >> 16) & 1u)) >> 16;
    return (short)r;
}
__device__ static inline float bf2f(short s) {
    return __uint_as_float(((uint32_t)(uint16_t)s) << 16);
}

// ---------------- Prep: W1T[n][d] = bf16(W1[d][n])  (1024 x 256) ----------
__global__ __launch_bounds__(256) void k_w1t_bf16(
    const float* __restrict__ W1, short* __restrict__ W1T)
{
    __shared__ float tile[32][33];
    const int bx = blockIdx.x;  // n tiles: 1024/32 = 32
    const int by = blockIdx.y;  // d tiles: 256/32 = 8
    const int tx = threadIdx.x, ty = threadIdx.y;  // (32, 8)
#pragma unroll
    for (int i = 0; i < 4; ++i)
        tile[ty + i * 8][tx] = W1[(by * 32 + ty + i * 8) * DIMH + bx * 32 + tx];
    __syncthreads();
#pragma unroll
    for (int i = 0; i < 4; ++i)
        W1T[(bx * 32 + ty + i * 8) * DIMD + by * 32 + tx] = f2bf(tile[tx][ty + i * 8]);
}

// ---------------- Prep: W2T[d][k] = bf16(W2[k][d])  (256 x 1024) ----------
__global__ __launch_bounds__(256) void k_w2t_bf16(
    const float* __restrict__ W2, short* __restrict__ W2T)
{
    __shared__ float tile[32][33];
    const int bx = blockIdx.x;  // k tiles: 1024/32 = 32
    const int by = blockIdx.y;  // d tiles: 256/32 = 8
    const int tx = threadIdx.x, ty = threadIdx.y;  // (32, 8)
#pragma unroll
    for (int i = 0; i < 4; ++i)
        tile[ty + i * 8][tx] = W2[(bx * 32 + ty + i * 8) * DIMD + by * 32 + tx];
    __syncthreads();
#pragma unroll
    for (int i = 0; i < 4; ++i)
        W2T[(by * 32 + ty + i * 8) * DIMH + bx * 32 + tx] = f2bf(tile[tx][ty + i * 8]);
}

// ---------------- Prep: W2B = bf16(W2) row-major; Zb0 = bf16(x) -----------
__global__ __launch_bounds__(256) void k_w2b_bf16(
    const float* __restrict__ W2, short* __restrict__ W2B)
{
    int idx = blockIdx.x * 256 + threadIdx.x;
    if (idx < DIMH * DIMD) W2B[idx] = f2bf(W2[idx]);
}
__global__ __launch_bounds__(256) void k_zb0(
    const float* __restrict__ x, short* __restrict__ zb)
{
    int idx = blockIdx.x * 256 + threadIdx.x;
    if (idx < BATCH * DIMD) zb[idx] = f2bf(x[idx]);
}

// ---------------- K1: h_bf = bf16(tanh(Zb @ W1T^T + t*W1[256] + b1)) ------
// MFMA 16x16x32. Block 256 thr = 4 waves; wave = 16 rows x 128 cols.
// Grid (4096/64, 1024/128) = (64, 8).
__global__ __launch_bounds__(256, 4) void k_pre(
    const short* __restrict__ Zb, const short* __restrict__ W1T,
    const float* __restrict__ W1, const float* __restrict__ b1, float tval,
    short* __restrict__ h_bf)
{
    const int t = threadIdx.x;
    const int wave = t >> 6, lane = t & 63;
    const int col = lane & 15, kq = lane >> 4;
    const int m0 = blockIdx.x * 64 + wave * 16;
    const int n0 = blockIdx.y * 128;

    short8 af[8];
#pragma unroll
    for (int ks = 0; ks < 8; ++ks)
        af[ks] = *(const short8*)&Zb[(m0 + col) * DIMD + ks * 32 + kq * 8];

    float4v acc[8];
#pragma unroll
    for (int ns = 0; ns < 8; ++ns) acc[ns] = (float4v){0.f, 0.f, 0.f, 0.f};

#pragma unroll
    for (int ns = 0; ns < 8; ++ns) {
        const int n = n0 + ns * 16 + col;
        const short* bp = &W1T[n * DIMD + kq * 8];
#pragma unroll
        for (int ks = 0; ks < 8; ++ks) {
            short8 bf = *(const short8*)&bp[ks * 32];
            acc[ns] = __builtin_amdgcn_mfma_f32_16x16x32_bf16(af[ks], bf, acc[ns], 0, 0, 0);
        }
    }
    // epilogue: + t*W1[256][n] + b1[n], tanh, store bf16
    // C layout: col = lane&15, row = kq*4 + r (verified m89/m91)
#pragma unroll
    for (int ns = 0; ns < 8; ++ns) {
        const int n = n0 + ns * 16 + col;
        const float add = tval * W1[DIMD * DIMH + n] + b1[n];
#pragma unroll
        for (int r = 0; r < 4; ++r) {
            const int m = m0 + kq * 4 + r;
            h_bf[m * DIMH + n] = f2bf(tanhf(acc[ns][r] + add));
        }
    }
}

// ---------------- K2: fz = Hb @ W2 + b2 (fp32 out); fuse Zb_next ----------
// MFMA 16x16x32, K=1024 pipelined. Block 256 thr = 4 waves; wave = 16 rows
// x 64 cols (waves tile N=256). Grid = 4096/16 = 256.
__global__ __launch_bounds__(256, 4) void k_fz2(
    const short* __restrict__ Hb, const short* __restrict__ W2T,
    const float* __restrict__ b2, const float* __restrict__ x,
    float* __restrict__ fz, float cnext, int write_zb, short* __restrict__ zb)
{
    const int t = threadIdx.x;
    const int wave = t >> 6, lane = t & 63;
    const int col = lane & 15, kq = lane >> 4;
    const int m0 = blockIdx.x * 16;
    const int n0 = wave * 64;

    float4v acc[4];
#pragma unroll
    for (int ns = 0; ns < 4; ++ns) acc[ns] = (float4v){0.f, 0.f, 0.f, 0.f};

    const short* ap = &Hb[(m0 + col) * DIMH + kq * 8];
    short8 a_cur = *(const short8*)ap;
    short8 b_cur[4];
#pragma unroll
    for (int ns = 0; ns < 4; ++ns)
        b_cur[ns] = *(const short8*)&W2T[(n0 + ns * 16 + col) * DIMH + kq * 8];

    for (int ks = 0; ks < 31; ++ks) {
        short8 a_nxt = *(const short8*)&ap[(ks + 1) * 32];
        short8 b_nxt[4];
#pragma unroll
        for (int ns = 0; ns < 4; ++ns)
            b_nxt[ns] = *(const short8*)&W2T[(n0 + ns * 16 + col) * DIMH + (ks + 1) * 32 + kq * 8];
#pragma unroll
        for (int ns = 0; ns < 4; ++ns)
            acc[ns] = __builtin_amdgcn_mfma_f32_16x16x32_bf16(a_cur, b_cur[ns], acc[ns], 0, 0, 0);
        a_cur = a_nxt;
#pragma unroll
        for (int ns = 0; ns < 4; ++ns) b_cur[ns] = b_nxt[ns];
    }
#pragma unroll
    for (int ns = 0; ns < 4; ++ns)
        acc[ns] = __builtin_amdgcn_mfma_f32_16x16x32_bf16(a_cur, b_cur[ns], acc[ns], 0, 0, 0);

#pragma unroll
    for (int ns = 0; ns < 4; ++ns) {
        const int n = n0 + ns * 16 + col;
        const float bias = b2[n];
#pragma unroll
        for (int r = 0; r < 4; ++r) {
            const int m = m0 + kq * 4 + r;
            const float val = acc[ns][r] + bias;
            fz[m * DIMD + n] = val;
            if (write_zb)
                zb[m * DIMD + n] = f2bf(x[m * DIMD + n] + cnext * val);
        }
    }
}

// ---------------- K3: fused Hutchinson probe via MFMA ---------------------
// Grid (10, 64), 512 threads = 8 waves. Every block covers the FULL n-range
// in identical ns-order (L2 convoying — R3-proven). Wave w owns
// n in [w*128, w*128+128): ns = 0..7. 8 waves/block fixes R3's latency bind.
__global__ __launch_bounds__(512, 4) void k_div_mfma(
    const short* __restrict__ W1T, const short* __restrict__ W2B,
    const short* __restrict__ Hb, float* __restrict__ divacc,
    uint32_t key0, uint32_t key1)
{
    __shared__ short E[64 * EPAD];
    const int t = threadIdx.x;
    const int probe = blockIdx.x;
    const int b0 = blockIdx.y * 64;

    // E tile (64 x 256) Rademacher bf16, split across 512 threads.
    // JAX partitionable threefry: bit[j] = (y0^y1)&1 of tf(k2, (0, j)).
    {
        const int ecol = t & 255;
        const int rbase = t >> 8;
#pragma unroll 2
        for (int i = 0; i < 32; ++i) {
            const int row = i * 2 + rbase;
            uint32_t j = (uint32_t)((probe * BATCH + b0 + row) * DIMD + ecol);
            uint32_t y0, y1;
            tf2x32(key0, key1, 0u, j, y0, y1);
            E[row * EPAD + ecol] = ((y0 ^ y1) & 1u) ? (short)0x3F80 : (short)0xBF80u;
        }
    }
    __syncthreads();

    const int wave = t >> 6, lane = t & 63;
    const int col = lane & 15, kq = lane >> 4;

    float rowacc[4][4];
#pragma unroll
    for (int a = 0; a < 4; ++a)
#pragma unroll
        for (int r = 0; r < 4; ++r) rowacc[a][r] = 0.0f;

    for (int ns = 0; ns < 8; ++ns) {
        const int n = wave * 128 + ns * 16 + col;
        const short8* bu = (const short8*)&W1T[n * DIMD + kq * 8];
        const short8* bv = (const short8*)&W2B[n * DIMD + kq * 8];
        short8 bufr[8], bvfr[8];
#pragma unroll
        for (int ks = 0; ks < 8; ++ks) { bufr[ks] = bu[ks * 4]; bvfr[ks] = bv[ks * 4]; }

#pragma unroll
        for (int ms = 0; ms < 4; ++ms) {
            const short* arow = &E[(ms * 16 + col) * EPAD + kq * 8];
            float4v u = {0.f, 0.f, 0.f, 0.f}, v = {0.f, 0.f, 0.f, 0.f};
#pragma unroll
            for (int ks = 0; ks < 8; ++ks) {
                short8 af = *(const short8*)&arow[ks * 32];
                u = __builtin_amdgcn_mfma_f32_16x16x32_bf16(af, bufr[ks], u, 0, 0, 0);
                v = __builtin_amdgcn_mfma_f32_16x16x32_bf16(af, bvfr[ks], v, 0, 0, 0);
            }
            // C layout: col = lane&15, row = kq*4 + r
#pragma unroll
            for (int r = 0; r < 4; ++r) {
                float hv = bf2f(Hb[(b0 + ms * 16 + kq * 4 + r) * DIMH + n]);
                float s = 1.0f - hv * hv;
                rowacc[ms][r] += u[r] * s * v[r];
            }
        }
    }

#pragma unroll
    for (int ms = 0; ms < 4; ++ms) {
#pragma unroll
        for (int r = 0; r < 4; ++r) {
            float p = rowacc[ms][r];
            p += __shfl_xor(p, 1, 64);
            p += __shfl_xor(p, 2, 64);
            p += __shfl_xor(p, 4, 64);
            p += __shfl_xor(p, 8, 64);
            rowacc[ms][r] = p;
        }
    }
    if (col == 0) {
#pragma unroll
        for (int ms = 0; ms < 4; ++ms)
#pragma unroll
            for (int r = 0; r < 4; ++r)
                atomicAdd(&divacc[b0 + ms * 16 + kq * 4 + r], rowacc[ms][r] * 0.1f);
    }
}

// ---------------- K4: RK4 combine + output --------------------------------
__global__ __launch_bounds__(256) void k_out(
    const float* __restrict__ x, const float* __restrict__ fz,
    const float* __restrict__ divacc, float* __restrict__ out)
{
    const int idx = blockIdx.x * 256 + threadIdx.x;
    const int TOT = BATCH * (DIMD + 1);
    if (idx >= TOT) return;
    const int b = idx / (DIMD + 1);
    const int c = idx - b * (DIMD + 1);
    const float sixth = 1.0f / 6.0f;
    if (c < DIMD) {
        float xv = x[b * DIMD + c];
        int o = b * DIMD + c;
        float f1 = fz[o];
        float f2 = fz[BATCH * DIMD + o];
        float f3 = fz[2 * BATCH * DIMD + o];
        float f4 = fz[3 * BATCH * DIMD + o];
        out[idx] = xv;
        out[TOT + idx] = xv + (f1 + 2.0f * f2 + 2.0f * f3 + f4) * sixth;
    } else {
        float d1 = divacc[b];
        float d2 = divacc[BATCH + b];
        float d3 = divacc[2 * BATCH + b];
        float d4 = divacc[3 * BATCH + b];
        out[idx] = 0.0f;
        out[TOT + idx] = -(d1 + 2.0f * d2 + 2.0f * d3 + d4) * sixth;
    }
}

// ---------------- launch ---------------------------------------------------
extern "C" void kernel_launch(void* const* d_in, const int* in_sizes, int n_in,
                              void* d_out, int out_size, void* d_ws, size_t ws_size,
                              hipStream_t stream) {
    const float* x  = (const float*)d_in[0];
    const float* W1 = (const float*)d_in[1];
    const float* b1 = (const float*)d_in[2];
    const float* W2 = (const float*)d_in[3];
    const float* b2 = (const float*)d_in[4];
    float* out = (float*)d_out;

    char* ws = (char*)d_ws;
    short* hb   = (short*)(ws);                    // 4096*1024*2 = 8 MiB
    float* fz   = (float*)(ws + 8388608);          // 4*4096*256*4 = 16 MiB
    short* zb   = (short*)(ws + 25165824);         // 4096*256*2 = 2 MiB
    short* w1t  = (short*)(ws + 27262976);         // 1024*256*2 = 512 KiB
    short* w2b  = (short*)(ws + 27787264);         // 1024*256*2 = 512 KiB
    short* w2t  = (short*)(ws + 28311552);         // 256*1024*2 = 512 KiB
    float* dv   = (float*)(ws + 28835840);         // 4*4096*4 = 64 KiB

    // Host-side threefry key derivation (partitionable semantics):
    //   fk_i = tf((0,42),(0,i));  k2_i = tf(fk_i,(0,1))
    uint32_t keys[4][2];
    for (uint32_t i = 0; i < 4; ++i) {
        uint32_t f0, f1, g0, g1;
        tf2x32(0u, 42u, 0u, i, f0, f1);
        tf2x32(f0, f1, 0u, 1u, g0, g1);
        keys[i][0] = g0;
        keys[i][1] = g1;
    }

    hipMemsetAsync(dv, 0, 4 * BATCH * sizeof(float), stream);

    k_w1t_bf16<<<dim3(32, 8), dim3(32, 8), 0, stream>>>(W1, w1t);
    k_w2t_bf16<<<dim3(32, 8), dim3(32, 8), 0, stream>>>(W2, w2t);
    k_w2b_bf16<<<(DIMH * DIMD + 255) / 256, 256, 0, stream>>>(W2, w2b);
    k_zb0<<<(BATCH * DIMD + 255) / 256, 256, 0, stream>>>(x, zb);

    const float tvals[4] = {0.0f, 0.5f, 0.5f, 1.0f};
    const float cnext[4] = {0.5f, 0.5f, 1.0f, 0.0f};  // Zb_{s+1} = x + cnext*fz_s
    for (int s = 0; s < 4; ++s) {
        k_pre<<<dim3(64, 8), 256, 0, stream>>>(zb, w1t, W1, b1, tvals[s], hb);
        k_div_mfma<<<dim3(10, 64), 512, 0, stream>>>(w1t, w2b, hb,
                                                     dv + (size_t)s * BATCH,
                                                     keys[s][0], keys[s][1]);
        k_fz2<<<256, 256, 0, stream>>>(hb, w2t, b2, x,
                                       fz + (size_t)s * BATCH * DIMD,
                                       cnext[s], (s < 3) ? 1 : 0, zb);
    }
    int tot = BATCH * (DIMD + 1);
    k_out<<<(tot + 255) / 256, 256, 0, stream>>>(x, fz, dv, out);
}

// Round 6
// 831.867 us; speedup vs baseline: 1.4242x; 1.4242x over previous
//
#include <hip/hip_runtime.h>
#include <stdint.h>

// Problem constants
#define BATCH 4096
#define DIMD  256
#define DIMH  1024
#define EPAD  264   // E tile row stride in bf16 elems (256 + 8 pad)

typedef __attribute__((ext_vector_type(8))) short short8;
typedef __attribute__((ext_vector_type(4))) float float4v;

// ---------------- threefry2x32 (JAX-compatible, 20 rounds) ----------------
__host__ __device__ static inline uint32_t rotl32(uint32_t v, int r) {
    return (v << r) | (v >> (32 - r));
}

__host__ __device__ static inline void tf2x32(uint32_t k0, uint32_t k1,
                                              uint32_t c0, uint32_t c1,
                                              uint32_t& o0, uint32_t& o1) {
    uint32_t ks0 = k0, ks1 = k1, ks2 = k0 ^ k1 ^ 0x1BD11BDAu;
    uint32_t x0 = c0 + ks0, x1 = c1 + ks1;
#define TF_R4(a, b, c, d)                                   \
    x0 += x1; x1 = rotl32(x1, a); x1 ^= x0;                 \
    x0 += x1; x1 = rotl32(x1, b); x1 ^= x0;                 \
    x0 += x1; x1 = rotl32(x1, c); x1 ^= x0;                 \
    x0 += x1; x1 = rotl32(x1, d); x1 ^= x0;
    TF_R4(13, 15, 26, 6)  x0 += ks1; x1 += ks2 + 1u;
    TF_R4(17, 29, 16, 24) x0 += ks2; x1 += ks0 + 2u;
    TF_R4(13, 15, 26, 6)  x0 += ks0; x1 += ks1 + 3u;
    TF_R4(17, 29, 16, 24) x0 += ks1; x1 += ks2 + 4u;
    TF_R4(13, 15, 26, 6)  x0 += ks2; x1 += ks0 + 5u;
#undef TF_R4
    o0 = x0; o1 = x1;
}

// float -> bf16 (round-to-nearest-even), bit pattern in a short
__device__ static inline short f2bf(float f) {
    uint32_t u = __float_as_uint(f);
    uint32_t r = (u + 0x7FFFu + ((u >> 16) & 1u)) >> 16;
    return (short)r;
}
__device__ static inline float bf2f(short s) {
    return __uint_as_float(((uint32_t)(uint16_t)s) << 16);
}

// ---------------- Prep: W1T[n][d] = bf16(W1[d][n])  (1024 x 256) ----------
__global__ __launch_bounds__(256) void k_w1t_bf16(
    const float* __restrict__ W1, short* __restrict__ W1T)
{
    __shared__ float tile[32][33];
    const int bx = blockIdx.x;  // n tiles: 1024/32 = 32
    const int by = blockIdx.y;  // d tiles: 256/32 = 8
    const int tx = threadIdx.x, ty = threadIdx.y;  // (32, 8)
#pragma unroll
    for (int i = 0; i < 4; ++i)
        tile[ty + i * 8][tx] = W1[(by * 32 + ty + i * 8) * DIMH + bx * 32 + tx];
    __syncthreads();
#pragma unroll
    for (int i = 0; i < 4; ++i)
        W1T[(bx * 32 + ty + i * 8) * DIMD + by * 32 + tx] = f2bf(tile[tx][ty + i * 8]);
}

// ---------------- Prep: W2T[d][k] = bf16(W2[k][d])  (256 x 1024) ----------
__global__ __launch_bounds__(256) void k_w2t_bf16(
    const float* __restrict__ W2, short* __restrict__ W2T)
{
    __shared__ float tile[32][33];
    const int bx = blockIdx.x;  // k tiles: 1024/32 = 32
    const int by = blockIdx.y;  // d tiles: 256/32 = 8
    const int tx = threadIdx.x, ty = threadIdx.y;  // (32, 8)
#pragma unroll
    for (int i = 0; i < 4; ++i)
        tile[ty + i * 8][tx] = W2[(bx * 32 + ty + i * 8) * DIMD + by * 32 + tx];
    __syncthreads();
#pragma unroll
    for (int i = 0; i < 4; ++i)
        W2T[(by * 32 + ty + i * 8) * DIMH + bx * 32 + tx] = f2bf(tile[tx][ty + i * 8]);
}

// ---------------- Prep: W2B = bf16(W2) row-major; Zb0 = bf16(x) -----------
__global__ __launch_bounds__(256) void k_w2b_bf16(
    const float* __restrict__ W2, short* __restrict__ W2B)
{
    int idx = blockIdx.x * 256 + threadIdx.x;
    if (idx < DIMH * DIMD) W2B[idx] = f2bf(W2[idx]);
}
__global__ __launch_bounds__(256) void k_zb0(
    const float* __restrict__ x, short* __restrict__ zb)
{
    int idx = blockIdx.x * 256 + threadIdx.x;
    if (idx < BATCH * DIMD) zb[idx] = f2bf(x[idx]);
}

// ---------------- K1: h_bf = bf16(tanh(Zb @ W1T^T + t*W1[256] + b1)) ------
// MFMA 16x16x32. Block 256 thr = 4 waves; wave = 16 rows x 128 cols.
// Grid (4096/64, 1024/128) = (64, 8). NOTE: no min-waves launch_bounds arg —
// the ",4" in R4/R5 capped VGPRs at 64 and spilled (the R4/R5 regression).
__global__ __launch_bounds__(256) void k_pre(
    const short* __restrict__ Zb, const short* __restrict__ W1T,
    const float* __restrict__ W1, const float* __restrict__ b1, float tval,
    short* __restrict__ h_bf)
{
    const int t = threadIdx.x;
    const int wave = t >> 6, lane = t & 63;
    const int col = lane & 15, kq = lane >> 4;
    const int m0 = blockIdx.x * 64 + wave * 16;
    const int n0 = blockIdx.y * 128;

    short8 af[8];
#pragma unroll
    for (int ks = 0; ks < 8; ++ks)
        af[ks] = *(const short8*)&Zb[(m0 + col) * DIMD + ks * 32 + kq * 8];

    float4v acc[8];
#pragma unroll
    for (int ns = 0; ns < 8; ++ns) acc[ns] = (float4v){0.f, 0.f, 0.f, 0.f};

#pragma unroll
    for (int ns = 0; ns < 8; ++ns) {
        const int n = n0 + ns * 16 + col;
        const short* bp = &W1T[n * DIMD + kq * 8];
#pragma unroll
        for (int ks = 0; ks < 8; ++ks) {
            short8 bf = *(const short8*)&bp[ks * 32];
            acc[ns] = __builtin_amdgcn_mfma_f32_16x16x32_bf16(af[ks], bf, acc[ns], 0, 0, 0);
        }
    }
    // epilogue: + t*W1[256][n] + b1[n], tanh, store bf16
    // C layout: col = lane&15, row = kq*4 + r (verified m89/m91)
#pragma unroll
    for (int ns = 0; ns < 8; ++ns) {
        const int n = n0 + ns * 16 + col;
        const float add = tval * W1[DIMD * DIMH + n] + b1[n];
#pragma unroll
        for (int r = 0; r < 4; ++r) {
            const int m = m0 + kq * 4 + r;
            h_bf[m * DIMH + n] = f2bf(tanhf(acc[ns][r] + add));
        }
    }
}

// ---------------- K2: fz = Hb @ W2 + b2 (fp32 out); fuse Zb_next ----------
// MFMA 16x16x32, K=1024 pipelined. Block 256 thr = 4 waves; wave = 16 rows
// x 64 cols (waves tile N=256). Grid = 4096/16 = 256.
__global__ __launch_bounds__(256) void k_fz2(
    const short* __restrict__ Hb, const short* __restrict__ W2T,
    const float* __restrict__ b2, const float* __restrict__ x,
    float* __restrict__ fz, float cnext, int write_zb, short* __restrict__ zb)
{
    const int t = threadIdx.x;
    const int wave = t >> 6, lane = t & 63;
    const int col = lane & 15, kq = lane >> 4;
    const int m0 = blockIdx.x * 16;
    const int n0 = wave * 64;

    float4v acc[4];
#pragma unroll
    for (int ns = 0; ns < 4; ++ns) acc[ns] = (float4v){0.f, 0.f, 0.f, 0.f};

    const short* ap = &Hb[(m0 + col) * DIMH + kq * 8];
    short8 a_cur = *(const short8*)ap;
    short8 b_cur[4];
#pragma unroll
    for (int ns = 0; ns < 4; ++ns)
        b_cur[ns] = *(const short8*)&W2T[(n0 + ns * 16 + col) * DIMH + kq * 8];

    for (int ks = 0; ks < 31; ++ks) {
        short8 a_nxt = *(const short8*)&ap[(ks + 1) * 32];
        short8 b_nxt[4];
#pragma unroll
        for (int ns = 0; ns < 4; ++ns)
            b_nxt[ns] = *(const short8*)&W2T[(n0 + ns * 16 + col) * DIMH + (ks + 1) * 32 + kq * 8];
#pragma unroll
        for (int ns = 0; ns < 4; ++ns)
            acc[ns] = __builtin_amdgcn_mfma_f32_16x16x32_bf16(a_cur, b_cur[ns], acc[ns], 0, 0, 0);
        a_cur = a_nxt;
#pragma unroll
        for (int ns = 0; ns < 4; ++ns) b_cur[ns] = b_nxt[ns];
    }
#pragma unroll
    for (int ns = 0; ns < 4; ++ns)
        acc[ns] = __builtin_amdgcn_mfma_f32_16x16x32_bf16(a_cur, b_cur[ns], acc[ns], 0, 0, 0);

#pragma unroll
    for (int ns = 0; ns < 4; ++ns) {
        const int n = n0 + ns * 16 + col;
        const float bias = b2[n];
#pragma unroll
        for (int r = 0; r < 4; ++r) {
            const int m = m0 + kq * 4 + r;
            const float val = acc[ns][r] + bias;
            fz[m * DIMD + n] = val;
            if (write_zb)
                zb[m * DIMD + n] = f2bf(x[m * DIMD + n] + cnext * val);
        }
    }
}

// ---------------- K3: fused Hutchinson probe via MFMA ---------------------
// R3 structure (proven 74 MB FETCH): grid (10, 64), 256 thr = 4 waves, wave
// owns n in [w*256, +256) (ns = 0..15, identical order in every block).
// New: double-buffered B-fragment prefetch ([2][8] regs, ns&1 index) to hide
// the ~200-cyc L2 latency behind the 64-MFMA (~307 cyc) body.
__global__ __launch_bounds__(256) void k_div_mfma(
    const short* __restrict__ W1T, const short* __restrict__ W2B,
    const short* __restrict__ Hb, float* __restrict__ divacc,
    uint32_t key0, uint32_t key1)
{
    __shared__ short E[64 * EPAD];
    const int t = threadIdx.x;
    const int probe = blockIdx.x;      // fastest-varying: 10 blocks share Hb tile in L2
    const int b0 = blockIdx.y * 64;

    // E tile (64 x 256) Rademacher bf16. JAX partitionable threefry:
    // bit[j] = (y0^y1)&1 of tf(k2, (0, j)).
#pragma unroll 2
    for (int i = 0; i < 64; ++i) {
        uint32_t j = (uint32_t)((probe * BATCH + b0 + i) * DIMD + t);
        uint32_t y0, y1;
        tf2x32(key0, key1, 0u, j, y0, y1);
        E[i * EPAD + t] = ((y0 ^ y1) & 1u) ? (short)0x3F80 : (short)0xBF80u;
    }
    __syncthreads();

    const int wave = t >> 6, lane = t & 63;
    const int col = lane & 15, kq = lane >> 4;

    float rowacc[4][4];
#pragma unroll
    for (int a = 0; a < 4; ++a)
#pragma unroll
        for (int r = 0; r < 4; ++r) rowacc[a][r] = 0.0f;

    short8 bufr[2][8], bvfr[2][8];
    // preload ns = 0
    {
        const int n = wave * 256 + col;
        const short8* bu = (const short8*)&W1T[n * DIMD + kq * 8];
        const short8* bv = (const short8*)&W2B[n * DIMD + kq * 8];
#pragma unroll
        for (int ks = 0; ks < 8; ++ks) { bufr[0][ks] = bu[ks * 4]; bvfr[0][ks] = bv[ks * 4]; }
    }

#pragma unroll 2
    for (int ns = 0; ns < 15; ++ns) {
        const int cur = ns & 1, nxt = cur ^ 1;
        // prefetch ns+1 B-fragments (independent of the MFMA body below)
        {
            const int n2 = wave * 256 + (ns + 1) * 16 + col;
            const short8* bu = (const short8*)&W1T[n2 * DIMD + kq * 8];
            const short8* bv = (const short8*)&W2B[n2 * DIMD + kq * 8];
#pragma unroll
            for (int ks = 0; ks < 8; ++ks) { bufr[nxt][ks] = bu[ks * 4]; bvfr[nxt][ks] = bv[ks * 4]; }
        }
        const int n = wave * 256 + ns * 16 + col;
#pragma unroll
        for (int ms = 0; ms < 4; ++ms) {
            const short* arow = &E[(ms * 16 + col) * EPAD + kq * 8];
            float4v u = {0.f, 0.f, 0.f, 0.f}, v = {0.f, 0.f, 0.f, 0.f};
#pragma unroll
            for (int ks = 0; ks < 8; ++ks) {
                short8 af = *(const short8*)&arow[ks * 32];
                u = __builtin_amdgcn_mfma_f32_16x16x32_bf16(af, bufr[cur][ks], u, 0, 0, 0);
                v = __builtin_amdgcn_mfma_f32_16x16x32_bf16(af, bvfr[cur][ks], v, 0, 0, 0);
            }
            // C layout: col = lane&15, row = kq*4 + r
#pragma unroll
            for (int r = 0; r < 4; ++r) {
                float hv = bf2f(Hb[(b0 + ms * 16 + kq * 4 + r) * DIMH + n]);
                float s = 1.0f - hv * hv;
                rowacc[ms][r] += u[r] * s * v[r];
            }
        }
    }
    // peeled last iteration: ns = 15 (cur buffer = 15&1 = 1)
    {
        const int n = wave * 256 + 15 * 16 + col;
#pragma unroll
        for (int ms = 0; ms < 4; ++ms) {
            const short* arow = &E[(ms * 16 + col) * EPAD + kq * 8];
            float4v u = {0.f, 0.f, 0.f, 0.f}, v = {0.f, 0.f, 0.f, 0.f};
#pragma unroll
            for (int ks = 0; ks < 8; ++ks) {
                short8 af = *(const short8*)&arow[ks * 32];
                u = __builtin_amdgcn_mfma_f32_16x16x32_bf16(af, bufr[1][ks], u, 0, 0, 0);
                v = __builtin_amdgcn_mfma_f32_16x16x32_bf16(af, bvfr[1][ks], v, 0, 0, 0);
            }
#pragma unroll
            for (int r = 0; r < 4; ++r) {
                float hv = bf2f(Hb[(b0 + ms * 16 + kq * 4 + r) * DIMH + n]);
                float s = 1.0f - hv * hv;
                rowacc[ms][r] += u[r] * s * v[r];
            }
        }
    }

#pragma unroll
    for (int ms = 0; ms < 4; ++ms) {
#pragma unroll
        for (int r = 0; r < 4; ++r) {
            float p = rowacc[ms][r];
            p += __shfl_xor(p, 1, 64);
            p += __shfl_xor(p, 2, 64);
            p += __shfl_xor(p, 4, 64);
            p += __shfl_xor(p, 8, 64);
            rowacc[ms][r] = p;
        }
    }
    if (col == 0) {
#pragma unroll
        for (int ms = 0; ms < 4; ++ms)
#pragma unroll
            for (int r = 0; r < 4; ++r)
                atomicAdd(&divacc[b0 + ms * 16 + kq * 4 + r], rowacc[ms][r] * 0.1f);
    }
}

// ---------------- K4: RK4 combine + output --------------------------------
__global__ __launch_bounds__(256) void k_out(
    const float* __restrict__ x, const float* __restrict__ fz,
    const float* __restrict__ divacc, float* __restrict__ out)
{
    const int idx = blockIdx.x * 256 + threadIdx.x;
    const int TOT = BATCH * (DIMD + 1);
    if (idx >= TOT) return;
    const int b = idx / (DIMD + 1);
    const int c = idx - b * (DIMD + 1);
    const float sixth = 1.0f / 6.0f;
    if (c < DIMD) {
        float xv = x[b * DIMD + c];
        int o = b * DIMD + c;
        float f1 = fz[o];
        float f2 = fz[BATCH * DIMD + o];
        float f3 = fz[2 * BATCH * DIMD + o];
        float f4 = fz[3 * BATCH * DIMD + o];
        out[idx] = xv;
        out[TOT + idx] = xv + (f1 + 2.0f * f2 + 2.0f * f3 + f4) * sixth;
    } else {
        float d1 = divacc[b];
        float d2 = divacc[BATCH + b];
        float d3 = divacc[2 * BATCH + b];
        float d4 = divacc[3 * BATCH + b];
        out[idx] = 0.0f;
        out[TOT + idx] = -(d1 + 2.0f * d2 + 2.0f * d3 + d4) * sixth;
    }
}

// ---------------- launch ---------------------------------------------------
extern "C" void kernel_launch(void* const* d_in, const int* in_sizes, int n_in,
                              void* d_out, int out_size, void* d_ws, size_t ws_size,
                              hipStream_t stream) {
    const float* x  = (const float*)d_in[0];
    const float* W1 = (const float*)d_in[1];
    const float* b1 = (const float*)d_in[2];
    const float* W2 = (const float*)d_in[3];
    const float* b2 = (const float*)d_in[4];
    float* out = (float*)d_out;

    char* ws = (char*)d_ws;
    short* hb   = (short*)(ws);                    // 4096*1024*2 = 8 MiB
    float* fz   = (float*)(ws + 8388608);          // 4*4096*256*4 = 16 MiB
    short* zb   = (short*)(ws + 25165824);         // 4096*256*2 = 2 MiB
    short* w1t  = (short*)(ws + 27262976);         // 1024*256*2 = 512 KiB
    short* w2b  = (short*)(ws + 27787264);         // 1024*256*2 = 512 KiB
    short* w2t  = (short*)(ws + 28311552);         // 256*1024*2 = 512 KiB
    float* dv   = (float*)(ws + 28835840);         // 4*4096*4 = 64 KiB

    // Host-side threefry key derivation (partitionable semantics):
    //   fk_i = tf((0,42),(0,i));  k2_i = tf(fk_i,(0,1))
    uint32_t keys[4][2];
    for (uint32_t i = 0; i < 4; ++i) {
        uint32_t f0, f1, g0, g1;
        tf2x32(0u, 42u, 0u, i, f0, f1);
        tf2x32(f0, f1, 0u, 1u, g0, g1);
        keys[i][0] = g0;
        keys[i][1] = g1;
    }

    hipMemsetAsync(dv, 0, 4 * BATCH * sizeof(float), stream);

    k_w1t_bf16<<<dim3(32, 8), dim3(32, 8), 0, stream>>>(W1, w1t);
    k_w2t_bf16<<<dim3(32, 8), dim3(32, 8), 0, stream>>>(W2, w2t);
    k_w2b_bf16<<<(DIMH * DIMD + 255) / 256, 256, 0, stream>>>(W2, w2b);
    k_zb0<<<(BATCH * DIMD + 255) / 256, 256, 0, stream>>>(x, zb);

    const float tvals[4] = {0.0f, 0.5f, 0.5f, 1.0f};
    const float cnext[4] = {0.5f, 0.5f, 1.0f, 0.0f};  // Zb_{s+1} = x + cnext*fz_s
    for (int s = 0; s < 4; ++s) {
        k_pre<<<dim3(64, 8), 256, 0, stream>>>(zb, w1t, W1, b1, tvals[s], hb);
        k_div_mfma<<<dim3(10, 64), 256, 0, stream>>>(w1t, w2b, hb,
                                                     dv + (size_t)s * BATCH,
                                                     keys[s][0], keys[s][1]);
        k_fz2<<<256, 256, 0, stream>>>(hb, w2t, b2, x,
                                       fz + (size_t)s * BATCH * DIMD,
                                       cnext[s], (s < 3) ? 1 : 0, zb);
    }
    int tot = BATCH * (DIMD + 1);
    k_out<<<(tot + 255) / 256, 256, 0, stream>>>(x, fz, dv, out);
}

// Round 7
// 719.868 us; speedup vs baseline: 1.6458x; 1.1556x over previous
//
#include <hip/hip_runtime.h>
#include <stdint.h>

// Problem constants
#define BATCH 4096
#define DIMD  256
#define DIMH  1024
#define EPAD  264   // E tile row stride in bf16 elems (256 + 8 pad)

typedef __attribute__((ext_vector_type(8))) short short8;
typedef __attribute__((ext_vector_type(4))) float float4v;

// ---------------- threefry2x32 (JAX-compatible, 20 rounds) ----------------
__host__ __device__ static inline uint32_t rotl32(uint32_t v, int r) {
    return (v << r) | (v >> (32 - r));
}

__host__ __device__ static inline void tf2x32(uint32_t k0, uint32_t k1,
                                              uint32_t c0, uint32_t c1,
                                              uint32_t& o0, uint32_t& o1) {
    uint32_t ks0 = k0, ks1 = k1, ks2 = k0 ^ k1 ^ 0x1BD11BDAu;
    uint32_t x0 = c0 + ks0, x1 = c1 + ks1;
#define TF_R4(a, b, c, d)                                   \
    x0 += x1; x1 = rotl32(x1, a); x1 ^= x0;                 \
    x0 += x1; x1 = rotl32(x1, b); x1 ^= x0;                 \
    x0 += x1; x1 = rotl32(x1, c); x1 ^= x0;                 \
    x0 += x1; x1 = rotl32(x1, d); x1 ^= x0;
    TF_R4(13, 15, 26, 6)  x0 += ks1; x1 += ks2 + 1u;
    TF_R4(17, 29, 16, 24) x0 += ks2; x1 += ks0 + 2u;
    TF_R4(13, 15, 26, 6)  x0 += ks0; x1 += ks1 + 3u;
    TF_R4(17, 29, 16, 24) x0 += ks1; x1 += ks2 + 4u;
    TF_R4(13, 15, 26, 6)  x0 += ks2; x1 += ks0 + 5u;
#undef TF_R4
    o0 = x0; o1 = x1;
}

// float -> bf16 (round-to-nearest-even), bit pattern in a short
__device__ static inline short f2bf(float f) {
    uint32_t u = __float_as_uint(f);
    uint32_t r = (u + 0x7FFFu + ((u >> 16) & 1u)) >> 16;
    return (short)r;
}
__device__ static inline float bf2f(short s) {
    return __uint_as_float(((uint32_t)(uint16_t)s) << 16);
}

// ---------------- Prep: W1T[n][d] = bf16(W1[d][n])  (1024 x 256) ----------
__global__ __launch_bounds__(256) void k_w1t_bf16(
    const float* __restrict__ W1, short* __restrict__ W1T)
{
    __shared__ float tile[32][33];
    const int bx = blockIdx.x;  // n tiles: 1024/32 = 32
    const int by = blockIdx.y;  // d tiles: 256/32 = 8
    const int tx = threadIdx.x, ty = threadIdx.y;  // (32, 8)
#pragma unroll
    for (int i = 0; i < 4; ++i)
        tile[ty + i * 8][tx] = W1[(by * 32 + ty + i * 8) * DIMH + bx * 32 + tx];
    __syncthreads();
#pragma unroll
    for (int i = 0; i < 4; ++i)
        W1T[(bx * 32 + ty + i * 8) * DIMD + by * 32 + tx] = f2bf(tile[tx][ty + i * 8]);
}

// ---------------- Prep: W2T[d][k] = bf16(W2[k][d])  (256 x 1024) ----------
__global__ __launch_bounds__(256) void k_w2t_bf16(
    const float* __restrict__ W2, short* __restrict__ W2T)
{
    __shared__ float tile[32][33];
    const int bx = blockIdx.x;  // k tiles: 1024/32 = 32
    const int by = blockIdx.y;  // d tiles: 256/32 = 8
    const int tx = threadIdx.x, ty = threadIdx.y;  // (32, 8)
#pragma unroll
    for (int i = 0; i < 4; ++i)
        tile[ty + i * 8][tx] = W2[(bx * 32 + ty + i * 8) * DIMD + by * 32 + tx];
    __syncthreads();
#pragma unroll
    for (int i = 0; i < 4; ++i)
        W2T[(by * 32 + ty + i * 8) * DIMH + bx * 32 + tx] = f2bf(tile[tx][ty + i * 8]);
}

// ---------------- Prep: W2B = bf16(W2) row-major; Zb0 = bf16(x) -----------
__global__ __launch_bounds__(256) void k_w2b_bf16(
    const float* __restrict__ W2, short* __restrict__ W2B)
{
    int idx = blockIdx.x * 256 + threadIdx.x;
    if (idx < DIMH * DIMD) W2B[idx] = f2bf(W2[idx]);
}
__global__ __launch_bounds__(256) void k_zb0(
    const float* __restrict__ x, short* __restrict__ zb)
{
    int idx = blockIdx.x * 256 + threadIdx.x;
    if (idx < BATCH * DIMD) zb[idx] = f2bf(x[idx]);
}

// ---------------- K1: h_bf = bf16(tanh(Zb @ W1T^T + t*W1[256] + b1)) ------
// MFMA 16x16x32. Block 256 thr = 4 waves; wave = 16 rows x 128 cols.
// Grid (4096/64, 1024/128) = (64, 8).
__global__ __launch_bounds__(256) void k_pre(
    const short* __restrict__ Zb, const short* __restrict__ W1T,
    const float* __restrict__ W1, const float* __restrict__ b1, float tval,
    short* __restrict__ h_bf)
{
    const int t = threadIdx.x;
    const int wave = t >> 6, lane = t & 63;
    const int col = lane & 15, kq = lane >> 4;
    const int m0 = blockIdx.x * 64 + wave * 16;
    const int n0 = blockIdx.y * 128;

    short8 af[8];
#pragma unroll
    for (int ks = 0; ks < 8; ++ks)
        af[ks] = *(const short8*)&Zb[(m0 + col) * DIMD + ks * 32 + kq * 8];

    float4v acc[8];
#pragma unroll
    for (int ns = 0; ns < 8; ++ns) acc[ns] = (float4v){0.f, 0.f, 0.f, 0.f};

#pragma unroll
    for (int ns = 0; ns < 8; ++ns) {
        const int n = n0 + ns * 16 + col;
        const short* bp = &W1T[n * DIMD + kq * 8];
#pragma unroll
        for (int ks = 0; ks < 8; ++ks) {
            short8 bf = *(const short8*)&bp[ks * 32];
            acc[ns] = __builtin_amdgcn_mfma_f32_16x16x32_bf16(af[ks], bf, acc[ns], 0, 0, 0);
        }
    }
    // epilogue: + t*W1[256][n] + b1[n], tanh, store bf16
    // C layout: col = lane&15, row = kq*4 + r (verified m89/m91)
#pragma unroll
    for (int ns = 0; ns < 8; ++ns) {
        const int n = n0 + ns * 16 + col;
        const float add = tval * W1[DIMD * DIMH + n] + b1[n];
#pragma unroll
        for (int r = 0; r < 4; ++r) {
            const int m = m0 + kq * 4 + r;
            h_bf[m * DIMH + n] = f2bf(tanhf(acc[ns][r] + add));
        }
    }
}

// ---------------- K2: fz = Hb @ W2 + b2 (fp32 out); fuse Zb_next ----------
// MFMA 16x16x32, K=1024 pipelined. Block 256 thr = 4 waves; wave = 16 rows
// x 64 cols (waves tile N=256). Grid = 4096/16 = 256.
__global__ __launch_bounds__(256) void k_fz2(
    const short* __restrict__ Hb, const short* __restrict__ W2T,
    const float* __restrict__ b2, const float* __restrict__ x,
    float* __restrict__ fz, float cnext, int write_zb, short* __restrict__ zb)
{
    const int t = threadIdx.x;
    const int wave = t >> 6, lane = t & 63;
    const int col = lane & 15, kq = lane >> 4;
    const int m0 = blockIdx.x * 16;
    const int n0 = wave * 64;

    float4v acc[4];
#pragma unroll
    for (int ns = 0; ns < 4; ++ns) acc[ns] = (float4v){0.f, 0.f, 0.f, 0.f};

    const short* ap = &Hb[(m0 + col) * DIMH + kq * 8];
    short8 a_cur = *(const short8*)ap;
    short8 b_cur[4];
#pragma unroll
    for (int ns = 0; ns < 4; ++ns)
        b_cur[ns] = *(const short8*)&W2T[(n0 + ns * 16 + col) * DIMH + kq * 8];

    for (int ks = 0; ks < 31; ++ks) {
        short8 a_nxt = *(const short8*)&ap[(ks + 1) * 32];
        short8 b_nxt[4];
#pragma unroll
        for (int ns = 0; ns < 4; ++ns)
            b_nxt[ns] = *(const short8*)&W2T[(n0 + ns * 16 + col) * DIMH + (ks + 1) * 32 + kq * 8];
#pragma unroll
        for (int ns = 0; ns < 4; ++ns)
            acc[ns] = __builtin_amdgcn_mfma_f32_16x16x32_bf16(a_cur, b_cur[ns], acc[ns], 0, 0, 0);
        a_cur = a_nxt;
#pragma unroll
        for (int ns = 0; ns < 4; ++ns) b_cur[ns] = b_nxt[ns];
    }
#pragma unroll
    for (int ns = 0; ns < 4; ++ns)
        acc[ns] = __builtin_amdgcn_mfma_f32_16x16x32_bf16(a_cur, b_cur[ns], acc[ns], 0, 0, 0);

#pragma unroll
    for (int ns = 0; ns < 4; ++ns) {
        const int n = n0 + ns * 16 + col;
        const float bias = b2[n];
#pragma unroll
        for (int r = 0; r < 4; ++r) {
            const int m = m0 + kq * 4 + r;
            const float val = acc[ns][r] + bias;
            fz[m * DIMD + n] = val;
            if (write_zb)
                zb[m * DIMD + n] = f2bf(x[m * DIMD + n] + cnext * val);
        }
    }
}

// ---------------- K3: fused Hutchinson probe via MFMA ---------------------
// Grid (20, 64): x = probe*2 + n-half, y = 64-row batch tile. 256 thr = 4
// waves; wave w owns n in [half*512 + w*128, +128): ns = 0..7.
// This is R4's structure WITHOUT the launch_bounds min-waves arg: the ",4"
// capped VGPRs at 64 and spilled 111 MB/dispatch to scratch (R4/R5
// regression). Natural allocation ~120 VGPR -> 4 waves/SIMD, 4 blocks/CU
// (LDS 33 KB also allows exactly 4) = 16 waves/CU.
__global__ __launch_bounds__(256) void k_div_mfma(
    const short* __restrict__ W1T, const short* __restrict__ W2B,
    const short* __restrict__ Hb, float* __restrict__ divacc,
    uint32_t key0, uint32_t key1)
{
    __shared__ short E[64 * EPAD];
    const int t = threadIdx.x;
    const int probe = blockIdx.x >> 1;
    const int half = blockIdx.x & 1;
    const int b0 = blockIdx.y * 64;

    // E tile (64 x 256) Rademacher bf16. JAX partitionable threefry:
    // bit[j] = (y0^y1)&1 of tf(k2, (0, j)).
#pragma unroll 2
    for (int i = 0; i < 64; ++i) {
        uint32_t j = (uint32_t)((probe * BATCH + b0 + i) * DIMD + t);
        uint32_t y0, y1;
        tf2x32(key0, key1, 0u, j, y0, y1);
        E[i * EPAD + t] = ((y0 ^ y1) & 1u) ? (short)0x3F80 : (short)0xBF80u;
    }
    __syncthreads();

    const int wave = t >> 6, lane = t & 63;
    const int col = lane & 15, kq = lane >> 4;

    float rowacc[4][4];
#pragma unroll
    for (int a = 0; a < 4; ++a)
#pragma unroll
        for (int r = 0; r < 4; ++r) rowacc[a][r] = 0.0f;

    for (int ns = 0; ns < 8; ++ns) {
        const int n = half * 512 + wave * 128 + ns * 16 + col;
        const short8* bu = (const short8*)&W1T[n * DIMD + kq * 8];
        const short8* bv = (const short8*)&W2B[n * DIMD + kq * 8];
        short8 bufr[8], bvfr[8];
#pragma unroll
        for (int ks = 0; ks < 8; ++ks) { bufr[ks] = bu[ks * 4]; bvfr[ks] = bv[ks * 4]; }

#pragma unroll
        for (int ms = 0; ms < 4; ++ms) {
            const short* arow = &E[(ms * 16 + col) * EPAD + kq * 8];
            float4v u = {0.f, 0.f, 0.f, 0.f}, v = {0.f, 0.f, 0.f, 0.f};
#pragma unroll
            for (int ks = 0; ks < 8; ++ks) {
                short8 af = *(const short8*)&arow[ks * 32];
                u = __builtin_amdgcn_mfma_f32_16x16x32_bf16(af, bufr[ks], u, 0, 0, 0);
                v = __builtin_amdgcn_mfma_f32_16x16x32_bf16(af, bvfr[ks], v, 0, 0, 0);
            }
            // C layout: col = lane&15, row = kq*4 + r
#pragma unroll
            for (int r = 0; r < 4; ++r) {
                float hv = bf2f(Hb[(b0 + ms * 16 + kq * 4 + r) * DIMH + n]);
                float s = 1.0f - hv * hv;
                rowacc[ms][r] += u[r] * s * v[r];
            }
        }
    }

#pragma unroll
    for (int ms = 0; ms < 4; ++ms) {
#pragma unroll
        for (int r = 0; r < 4; ++r) {
            float p = rowacc[ms][r];
            p += __shfl_xor(p, 1, 64);
            p += __shfl_xor(p, 2, 64);
            p += __shfl_xor(p, 4, 64);
            p += __shfl_xor(p, 8, 64);
            rowacc[ms][r] = p;
        }
    }
    if (col == 0) {
#pragma unroll
        for (int ms = 0; ms < 4; ++ms)
#pragma unroll
            for (int r = 0; r < 4; ++r)
                atomicAdd(&divacc[b0 + ms * 16 + kq * 4 + r], rowacc[ms][r] * 0.1f);
    }
}

// ---------------- K4: RK4 combine + output --------------------------------
__global__ __launch_bounds__(256) void k_out(
    const float* __restrict__ x, const float* __restrict__ fz,
    const float* __restrict__ divacc, float* __restrict__ out)
{
    const int idx = blockIdx.x * 256 + threadIdx.x;
    const int TOT = BATCH * (DIMD + 1);
    if (idx >= TOT) return;
    const int b = idx / (DIMD + 1);
    const int c = idx - b * (DIMD + 1);
    const float sixth = 1.0f / 6.0f;
    if (c < DIMD) {
        float xv = x[b * DIMD + c];
        int o = b * DIMD + c;
        float f1 = fz[o];
        float f2 = fz[BATCH * DIMD + o];
        float f3 = fz[2 * BATCH * DIMD + o];
        float f4 = fz[3 * BATCH * DIMD + o];
        out[idx] = xv;
        out[TOT + idx] = xv + (f1 + 2.0f * f2 + 2.0f * f3 + f4) * sixth;
    } else {
        float d1 = divacc[b];
        float d2 = divacc[BATCH + b];
        float d3 = divacc[2 * BATCH + b];
        float d4 = divacc[3 * BATCH + b];
        out[idx] = 0.0f;
        out[TOT + idx] = -(d1 + 2.0f * d2 + 2.0f * d3 + d4) * sixth;
    }
}

// ---------------- launch ---------------------------------------------------
extern "C" void kernel_launch(void* const* d_in, const int* in_sizes, int n_in,
                              void* d_out, int out_size, void* d_ws, size_t ws_size,
                              hipStream_t stream) {
    const float* x  = (const float*)d_in[0];
    const float* W1 = (const float*)d_in[1];
    const float* b1 = (const float*)d_in[2];
    const float* W2 = (const float*)d_in[3];
    const float* b2 = (const float*)d_in[4];
    float* out = (float*)d_out;

    char* ws = (char*)d_ws;
    short* hb   = (short*)(ws);                    // 4096*1024*2 = 8 MiB
    float* fz   = (float*)(ws + 8388608);          // 4*4096*256*4 = 16 MiB
    short* zb   = (short*)(ws + 25165824);         // 4096*256*2 = 2 MiB
    short* w1t  = (short*)(ws + 27262976);         // 1024*256*2 = 512 KiB
    short* w2b  = (short*)(ws + 27787264);         // 1024*256*2 = 512 KiB
    short* w2t  = (short*)(ws + 28311552);         // 256*1024*2 = 512 KiB
    float* dv   = (float*)(ws + 28835840);         // 4*4096*4 = 64 KiB

    // Host-side threefry key derivation (partitionable semantics):
    //   fk_i = tf((0,42),(0,i));  k2_i = tf(fk_i,(0,1))
    uint32_t keys[4][2];
    for (uint32_t i = 0; i < 4; ++i) {
        uint32_t f0, f1, g0, g1;
        tf2x32(0u, 42u, 0u, i, f0, f1);
        tf2x32(f0, f1, 0u, 1u, g0, g1);
        keys[i][0] = g0;
        keys[i][1] = g1;
    }

    hipMemsetAsync(dv, 0, 4 * BATCH * sizeof(float), stream);

    k_w1t_bf16<<<dim3(32, 8), dim3(32, 8), 0, stream>>>(W1, w1t);
    k_w2t_bf16<<<dim3(32, 8), dim3(32, 8), 0, stream>>>(W2, w2t);
    k_w2b_bf16<<<(DIMH * DIMD + 255) / 256, 256, 0, stream>>>(W2, w2b);
    k_zb0<<<(BATCH * DIMD + 255) / 256, 256, 0, stream>>>(x, zb);

    const float tvals[4] = {0.0f, 0.5f, 0.5f, 1.0f};
    const float cnext[4] = {0.5f, 0.5f, 1.0f, 0.0f};  // Zb_{s+1} = x + cnext*fz_s
    for (int s = 0; s < 4; ++s) {
        k_pre<<<dim3(64, 8), 256, 0, stream>>>(zb, w1t, W1, b1, tvals[s], hb);
        k_div_mfma<<<dim3(20, 64), 256, 0, stream>>>(w1t, w2b, hb,
                                                     dv + (size_t)s * BATCH,
                                                     keys[s][0], keys[s][1]);
        k_fz2<<<256, 256, 0, stream>>>(hb, w2t, b2, x,
                                       fz + (size_t)s * BATCH * DIMD,
                                       cnext[s], (s < 3) ? 1 : 0, zb);
    }
    int tot = BATCH * (DIMD + 1);
    k_out<<<(tot + 255) / 256, 256, 0, stream>>>(x, fz, dv, out);
}

// Round 8
// 592.391 us; speedup vs baseline: 1.9999x; 1.2152x over previous
//
#include <hip/hip_runtime.h>
#include <stdint.h>

// Problem constants
#define BATCH 4096
#define DIMD  256
#define DIMH  1024
#define EPAD  264   // E tile row stride in bf16 elems (256 + 8 pad)

typedef __attribute__((ext_vector_type(8))) short short8;
typedef __attribute__((ext_vector_type(4))) float float4v;

// ---------------- threefry2x32 (JAX-compatible, 20 rounds) ----------------
__host__ __device__ static inline uint32_t rotl32(uint32_t v, int r) {
    return (v << r) | (v >> (32 - r));
}

__host__ __device__ static inline void tf2x32(uint32_t k0, uint32_t k1,
                                              uint32_t c0, uint32_t c1,
                                              uint32_t& o0, uint32_t& o1) {
    uint32_t ks0 = k0, ks1 = k1, ks2 = k0 ^ k1 ^ 0x1BD11BDAu;
    uint32_t x0 = c0 + ks0, x1 = c1 + ks1;
#define TF_R4(a, b, c, d)                                   \
    x0 += x1; x1 = rotl32(x1, a); x1 ^= x0;                 \
    x0 += x1; x1 = rotl32(x1, b); x1 ^= x0;                 \
    x0 += x1; x1 = rotl32(x1, c); x1 ^= x0;                 \
    x0 += x1; x1 = rotl32(x1, d); x1 ^= x0;
    TF_R4(13, 15, 26, 6)  x0 += ks1; x1 += ks2 + 1u;
    TF_R4(17, 29, 16, 24) x0 += ks2; x1 += ks0 + 2u;
    TF_R4(13, 15, 26, 6)  x0 += ks0; x1 += ks1 + 3u;
    TF_R4(17, 29, 16, 24) x0 += ks1; x1 += ks2 + 4u;
    TF_R4(13, 15, 26, 6)  x0 += ks2; x1 += ks0 + 5u;
#undef TF_R4
    o0 = x0; o1 = x1;
}

// float -> bf16 (round-to-nearest-even), bit pattern in a short
__device__ static inline short f2bf(float f) {
    uint32_t u = __float_as_uint(f);
    uint32_t r = (u + 0x7FFFu + ((u >> 16) & 1u)) >> 16;
    return (short)r;
}
__device__ static inline float bf2f(short s) {
    return __uint_as_float(((uint32_t)(uint16_t)s) << 16);
}

// ---------------- Prep: W1T[n][d] = bf16(W1[d][n])  (1024 x 256) ----------
__global__ __launch_bounds__(256) void k_w1t_bf16(
    const float* __restrict__ W1, short* __restrict__ W1T)
{
    __shared__ float tile[32][33];
    const int bx = blockIdx.x;  // n tiles: 1024/32 = 32
    const int by = blockIdx.y;  // d tiles: 256/32 = 8
    const int tx = threadIdx.x, ty = threadIdx.y;  // (32, 8)
#pragma unroll
    for (int i = 0; i < 4; ++i)
        tile[ty + i * 8][tx] = W1[(by * 32 + ty + i * 8) * DIMH + bx * 32 + tx];
    __syncthreads();
#pragma unroll
    for (int i = 0; i < 4; ++i)
        W1T[(bx * 32 + ty + i * 8) * DIMD + by * 32 + tx] = f2bf(tile[tx][ty + i * 8]);
}

// ---------------- Prep: W2T[d][k] = bf16(W2[k][d])  (256 x 1024) ----------
__global__ __launch_bounds__(256) void k_w2t_bf16(
    const float* __restrict__ W2, short* __restrict__ W2T)
{
    __shared__ float tile[32][33];
    const int bx = blockIdx.x;  // k tiles: 1024/32 = 32
    const int by = blockIdx.y;  // d tiles: 256/32 = 8
    const int tx = threadIdx.x, ty = threadIdx.y;  // (32, 8)
#pragma unroll
    for (int i = 0; i < 4; ++i)
        tile[ty + i * 8][tx] = W2[(bx * 32 + ty + i * 8) * DIMD + by * 32 + tx];
    __syncthreads();
#pragma unroll
    for (int i = 0; i < 4; ++i)
        W2T[(by * 32 + ty + i * 8) * DIMH + bx * 32 + tx] = f2bf(tile[tx][ty + i * 8]);
}

// ---------------- Prep: W2B = bf16(W2) row-major; Zb0 = bf16(x) -----------
__global__ __launch_bounds__(256) void k_w2b_bf16(
    const float* __restrict__ W2, short* __restrict__ W2B)
{
    int idx = blockIdx.x * 256 + threadIdx.x;
    if (idx < DIMH * DIMD) W2B[idx] = f2bf(W2[idx]);
}
__global__ __launch_bounds__(256) void k_zb0(
    const float* __restrict__ x, short* __restrict__ zb)
{
    int idx = blockIdx.x * 256 + threadIdx.x;
    if (idx < BATCH * DIMD) zb[idx] = f2bf(x[idx]);
}

// ---------------- E-gen: pack Rademacher bits, 1 bit/element --------------
// bit[j] = (y0^y1)&1 of tf(k2, (0, j)), j flat over (10, 4096, 256).
// Word w holds elements j = w*64 + laneid (ballot bit i = lane i).
// 40960 blocks x 256 thr, one element per thread.
__global__ __launch_bounds__(256) void k_egen(
    uint64_t* __restrict__ Ep, uint32_t key0, uint32_t key1)
{
    const uint32_t j = blockIdx.x * 256 + threadIdx.x;
    uint32_t y0, y1;
    tf2x32(key0, key1, 0u, j, y0, y1);
    uint64_t mask = __ballot(((y0 ^ y1) & 1u) != 0u);
    if ((threadIdx.x & 63) == 0)
        Ep[j >> 6] = mask;
}

// ---------------- K1: h_bf = bf16(tanh(Zb @ W1T^T + t*W1[256] + b1)) ------
// MFMA 16x16x32. Block 256 thr = 4 waves; wave = 16 rows x 128 cols.
// Grid (4096/64, 1024/128) = (64, 8).
__global__ __launch_bounds__(256) void k_pre(
    const short* __restrict__ Zb, const short* __restrict__ W1T,
    const float* __restrict__ W1, const float* __restrict__ b1, float tval,
    short* __restrict__ h_bf)
{
    const int t = threadIdx.x;
    const int wave = t >> 6, lane = t & 63;
    const int col = lane & 15, kq = lane >> 4;
    const int m0 = blockIdx.x * 64 + wave * 16;
    const int n0 = blockIdx.y * 128;

    short8 af[8];
#pragma unroll
    for (int ks = 0; ks < 8; ++ks)
        af[ks] = *(const short8*)&Zb[(m0 + col) * DIMD + ks * 32 + kq * 8];

    float4v acc[8];
#pragma unroll
    for (int ns = 0; ns < 8; ++ns) acc[ns] = (float4v){0.f, 0.f, 0.f, 0.f};

#pragma unroll
    for (int ns = 0; ns < 8; ++ns) {
        const int n = n0 + ns * 16 + col;
        const short* bp = &W1T[n * DIMD + kq * 8];
#pragma unroll
        for (int ks = 0; ks < 8; ++ks) {
            short8 bf = *(const short8*)&bp[ks * 32];
            acc[ns] = __builtin_amdgcn_mfma_f32_16x16x32_bf16(af[ks], bf, acc[ns], 0, 0, 0);
        }
    }
    // epilogue: + t*W1[256][n] + b1[n], tanh, store bf16
    // C layout: col = lane&15, row = kq*4 + r (verified m89/m91)
#pragma unroll
    for (int ns = 0; ns < 8; ++ns) {
        const int n = n0 + ns * 16 + col;
        const float add = tval * W1[DIMD * DIMH + n] + b1[n];
#pragma unroll
        for (int r = 0; r < 4; ++r) {
            const int m = m0 + kq * 4 + r;
            h_bf[m * DIMH + n] = f2bf(tanhf(acc[ns][r] + add));
        }
    }
}

// ---------------- K2: fz = Hb @ W2 + b2 (fp32 out); fuse Zb_next ----------
// MFMA 16x16x32, K=1024 pipelined. Block 256 thr = 4 waves; wave = 16 rows
// x 64 cols (waves tile N=256). Grid = 4096/16 = 256.
__global__ __launch_bounds__(256) void k_fz2(
    const short* __restrict__ Hb, const short* __restrict__ W2T,
    const float* __restrict__ b2, const float* __restrict__ x,
    float* __restrict__ fz, float cnext, int write_zb, short* __restrict__ zb)
{
    const int t = threadIdx.x;
    const int wave = t >> 6, lane = t & 63;
    const int col = lane & 15, kq = lane >> 4;
    const int m0 = blockIdx.x * 16;
    const int n0 = wave * 64;

    float4v acc[4];
#pragma unroll
    for (int ns = 0; ns < 4; ++ns) acc[ns] = (float4v){0.f, 0.f, 0.f, 0.f};

    const short* ap = &Hb[(m0 + col) * DIMH + kq * 8];
    short8 a_cur = *(const short8*)ap;
    short8 b_cur[4];
#pragma unroll
    for (int ns = 0; ns < 4; ++ns)
        b_cur[ns] = *(const short8*)&W2T[(n0 + ns * 16 + col) * DIMH + kq * 8];

    for (int ks = 0; ks < 31; ++ks) {
        short8 a_nxt = *(const short8*)&ap[(ks + 1) * 32];
        short8 b_nxt[4];
#pragma unroll
        for (int ns = 0; ns < 4; ++ns)
            b_nxt[ns] = *(const short8*)&W2T[(n0 + ns * 16 + col) * DIMH + (ks + 1) * 32 + kq * 8];
#pragma unroll
        for (int ns = 0; ns < 4; ++ns)
            acc[ns] = __builtin_amdgcn_mfma_f32_16x16x32_bf16(a_cur, b_cur[ns], acc[ns], 0, 0, 0);
        a_cur = a_nxt;
#pragma unroll
        for (int ns = 0; ns < 4; ++ns) b_cur[ns] = b_nxt[ns];
    }
#pragma unroll
    for (int ns = 0; ns < 4; ++ns)
        acc[ns] = __builtin_amdgcn_mfma_f32_16x16x32_bf16(a_cur, b_cur[ns], acc[ns], 0, 0, 0);

#pragma unroll
    for (int ns = 0; ns < 4; ++ns) {
        const int n = n0 + ns * 16 + col;
        const float bias = b2[n];
#pragma unroll
        for (int r = 0; r < 4; ++r) {
            const int m = m0 + kq * 4 + r;
            const float val = acc[ns][r] + bias;
            fz[m * DIMD + n] = val;
            if (write_zb)
                zb[m * DIMD + n] = f2bf(x[m * DIMD + n] + cnext * val);
        }
    }
}

// ---------------- K3: fused Hutchinson probe via MFMA (v2) ----------------
// Grid (16 n-tiles, 64 batch-tiles) = 1024 blocks (4/CU). 256 thr = 4 waves.
// Wave w owns ONE 16-wide n-subtile: n = nt*64 + w*16 + col. B-frags loaded
// once per kernel (64 VGPR); s = 1-h^2 register-cached (16 VGPR, reused
// across all 10 probes). Per probe: expand 2 KB packed bits -> LDS E tile
// (replaces R7's 4800-inst/thread PRNG), barrier, 4 ms x 16 MFMA.
__global__ __launch_bounds__(256) void k_div2(
    const short* __restrict__ W1T, const short* __restrict__ W2B,
    const short* __restrict__ Hb, const uint64_t* __restrict__ Ep,
    float* __restrict__ divacc)
{
    __shared__ short E[64 * EPAD];
    const int t = threadIdx.x;
    const int nt = blockIdx.x;         // fastest-varying: 16 blocks share E/Hb rows
    const int b0 = blockIdx.y * 64;
    const int wave = t >> 6, lane = t & 63;
    const int col = lane & 15, kq = lane >> 4;
    const int n = nt * 64 + wave * 16 + col;

    // B-fragments: once per kernel
    short8 bufr[8], bvfr[8];
#pragma unroll
    for (int ks = 0; ks < 8; ++ks) {
        bufr[ks] = *(const short8*)&W1T[n * DIMD + ks * 32 + kq * 8];
        bvfr[ks] = *(const short8*)&W2B[n * DIMD + ks * 32 + kq * 8];
    }

    // s = 1 - h^2 register cache: rows ms*16 + kq*4 + r, col n
    float sreg[4][4];
#pragma unroll
    for (int ms = 0; ms < 4; ++ms)
#pragma unroll
        for (int r = 0; r < 4; ++r) {
            float hv = bf2f(Hb[(b0 + ms * 16 + kq * 4 + r) * DIMH + n]);
            sreg[ms][r] = 1.0f - hv * hv;
        }

    float rowacc[4][4];
#pragma unroll
    for (int a = 0; a < 4; ++a)
#pragma unroll
        for (int r = 0; r < 4; ++r) rowacc[a][r] = 0.0f;

    // bit-expansion mapping: thread t expands word (probe*4096+b0)*4 + t
    // covering row = t>>2, cols [(t&3)*64, +64)
    const int erow = t >> 2, ecol = (t & 3) * 64;
    short* const edst = &E[erow * EPAD + ecol];

#pragma unroll 1
    for (int probe = 0; probe < 10; ++probe) {
        __syncthreads();   // previous probe's readers done before overwrite
        uint64_t w = Ep[(size_t)(probe * BATCH + b0) * 4 + t];
#pragma unroll
        for (int i = 0; i < 8; ++i) {
            short8 val;
#pragma unroll
            for (int k = 0; k < 8; ++k)
                val[k] = ((w >> (i * 8 + k)) & 1ull) ? (short)0x3F80 : (short)0xBF80u;
            *(short8*)&edst[i * 8] = val;
        }
        __syncthreads();

#pragma unroll
        for (int ms = 0; ms < 4; ++ms) {
            const short* arow = &E[(ms * 16 + col) * EPAD + kq * 8];
            float4v u = {0.f, 0.f, 0.f, 0.f}, v = {0.f, 0.f, 0.f, 0.f};
#pragma unroll
            for (int ks = 0; ks < 8; ++ks) {
                short8 af = *(const short8*)&arow[ks * 32];
                u = __builtin_amdgcn_mfma_f32_16x16x32_bf16(af, bufr[ks], u, 0, 0, 0);
                v = __builtin_amdgcn_mfma_f32_16x16x32_bf16(af, bvfr[ks], v, 0, 0, 0);
            }
            // C layout: col = lane&15, row = kq*4 + r
#pragma unroll
            for (int r = 0; r < 4; ++r)
                rowacc[ms][r] += u[r] * sreg[ms][r] * v[r];
        }
    }

#pragma unroll
    for (int ms = 0; ms < 4; ++ms) {
#pragma unroll
        for (int r = 0; r < 4; ++r) {
            float p = rowacc[ms][r];
            p += __shfl_xor(p, 1, 64);
            p += __shfl_xor(p, 2, 64);
            p += __shfl_xor(p, 4, 64);
            p += __shfl_xor(p, 8, 64);
            rowacc[ms][r] = p;
        }
    }
    if (col == 0) {
#pragma unroll
        for (int ms = 0; ms < 4; ++ms)
#pragma unroll
            for (int r = 0; r < 4; ++r)
                atomicAdd(&divacc[b0 + ms * 16 + kq * 4 + r], rowacc[ms][r] * 0.1f);
    }
}

// ---------------- K4: RK4 combine + output --------------------------------
__global__ __launch_bounds__(256) void k_out(
    const float* __restrict__ x, const float* __restrict__ fz,
    const float* __restrict__ divacc, float* __restrict__ out)
{
    const int idx = blockIdx.x * 256 + threadIdx.x;
    const int TOT = BATCH * (DIMD + 1);
    if (idx >= TOT) return;
    const int b = idx / (DIMD + 1);
    const int c = idx - b * (DIMD + 1);
    const float sixth = 1.0f / 6.0f;
    if (c < DIMD) {
        float xv = x[b * DIMD + c];
        int o = b * DIMD + c;
        float f1 = fz[o];
        float f2 = fz[BATCH * DIMD + o];
        float f3 = fz[2 * BATCH * DIMD + o];
        float f4 = fz[3 * BATCH * DIMD + o];
        out[idx] = xv;
        out[TOT + idx] = xv + (f1 + 2.0f * f2 + 2.0f * f3 + f4) * sixth;
    } else {
        float d1 = divacc[b];
        float d2 = divacc[BATCH + b];
        float d3 = divacc[2 * BATCH + b];
        float d4 = divacc[3 * BATCH + b];
        out[idx] = 0.0f;
        out[TOT + idx] = -(d1 + 2.0f * d2 + 2.0f * d3 + d4) * sixth;
    }
}

// ---------------- launch ---------------------------------------------------
extern "C" void kernel_launch(void* const* d_in, const int* in_sizes, int n_in,
                              void* d_out, int out_size, void* d_ws, size_t ws_size,
                              hipStream_t stream) {
    const float* x  = (const float*)d_in[0];
    const float* W1 = (const float*)d_in[1];
    const float* b1 = (const float*)d_in[2];
    const float* W2 = (const float*)d_in[3];
    const float* b2 = (const float*)d_in[4];
    float* out = (float*)d_out;

    char* ws = (char*)d_ws;
    short* hb   = (short*)(ws);                    // 4096*1024*2 = 8 MiB
    float* fz   = (float*)(ws + 8388608);          // 4*4096*256*4 = 16 MiB
    short* zb   = (short*)(ws + 25165824);         // 4096*256*2 = 2 MiB
    short* w1t  = (short*)(ws + 27262976);         // 1024*256*2 = 512 KiB
    short* w2b  = (short*)(ws + 27787264);         // 1024*256*2 = 512 KiB
    short* w2t  = (short*)(ws + 28311552);         // 256*1024*2 = 512 KiB
    float* dv   = (float*)(ws + 28835840);         // 4*4096*4 = 64 KiB
    uint64_t* ep = (uint64_t*)(ws + 28901376);     // 10*4096*256/8 = 1.25 MiB

    // Host-side threefry key derivation (partitionable semantics):
    //   fk_i = tf((0,42),(0,i));  k2_i = tf(fk_i,(0,1))
    uint32_t keys[4][2];
    for (uint32_t i = 0; i < 4; ++i) {
        uint32_t f0, f1, g0, g1;
        tf2x32(0u, 42u, 0u, i, f0, f1);
        tf2x32(f0, f1, 0u, 1u, g0, g1);
        keys[i][0] = g0;
        keys[i][1] = g1;
    }

    hipMemsetAsync(dv, 0, 4 * BATCH * sizeof(float), stream);

    k_w1t_bf16<<<dim3(32, 8), dim3(32, 8), 0, stream>>>(W1, w1t);
    k_w2t_bf16<<<dim3(32, 8), dim3(32, 8), 0, stream>>>(W2, w2t);
    k_w2b_bf16<<<(DIMH * DIMD + 255) / 256, 256, 0, stream>>>(W2, w2b);
    k_zb0<<<(BATCH * DIMD + 255) / 256, 256, 0, stream>>>(x, zb);

    const float tvals[4] = {0.0f, 0.5f, 0.5f, 1.0f};
    const float cnext[4] = {0.5f, 0.5f, 1.0f, 0.0f};  // Zb_{s+1} = x + cnext*fz_s
    const int NEL = 10 * BATCH * DIMD;
    for (int s = 0; s < 4; ++s) {
        k_egen<<<NEL / 256, 256, 0, stream>>>(ep, keys[s][0], keys[s][1]);
        k_pre<<<dim3(64, 8), 256, 0, stream>>>(zb, w1t, W1, b1, tvals[s], hb);
        k_div2<<<dim3(16, 64), 256, 0, stream>>>(w1t, w2b, hb, ep,
                                                 dv + (size_t)s * BATCH);
        k_fz2<<<256, 256, 0, stream>>>(hb, w2t, b2, x,
                                       fz + (size_t)s * BATCH * DIMD,
                                       cnext[s], (s < 3) ? 1 : 0, zb);
    }
    int tot = BATCH * (DIMD + 1);
    k_out<<<(tot + 255) / 256, 256, 0, stream>>>(x, fz, dv, out);
}

// Round 9
// 523.927 us; speedup vs baseline: 2.2613x; 1.1307x over previous
//
#include <hip/hip_runtime.h>
#include <stdint.h>

// Problem constants
#define BATCH 4096
#define DIMD  256
#define DIMH  1024
#define EPAD  264       // E tile row stride in bf16 elems (256 + 8 pad)
#define NEPW  163840    // packed words per stage: 10*4096*256/64

typedef __attribute__((ext_vector_type(8))) short short8;
typedef __attribute__((ext_vector_type(4))) float float4v;

struct Keys4 { uint32_t a[4]; uint32_t b[4]; };

// ---------------- threefry2x32 (JAX-compatible, 20 rounds) ----------------
__host__ __device__ static inline uint32_t rotl32(uint32_t v, int r) {
    return (v << r) | (v >> (32 - r));
}

__host__ __device__ static inline void tf2x32(uint32_t k0, uint32_t k1,
                                              uint32_t c0, uint32_t c1,
                                              uint32_t& o0, uint32_t& o1) {
    uint32_t ks0 = k0, ks1 = k1, ks2 = k0 ^ k1 ^ 0x1BD11BDAu;
    uint32_t x0 = c0 + ks0, x1 = c1 + ks1;
#define TF_R4(a, b, c, d)                                   \
    x0 += x1; x1 = rotl32(x1, a); x1 ^= x0;                 \
    x0 += x1; x1 = rotl32(x1, b); x1 ^= x0;                 \
    x0 += x1; x1 = rotl32(x1, c); x1 ^= x0;                 \
    x0 += x1; x1 = rotl32(x1, d); x1 ^= x0;
    TF_R4(13, 15, 26, 6)  x0 += ks1; x1 += ks2 + 1u;
    TF_R4(17, 29, 16, 24) x0 += ks2; x1 += ks0 + 2u;
    TF_R4(13, 15, 26, 6)  x0 += ks0; x1 += ks1 + 3u;
    TF_R4(17, 29, 16, 24) x0 += ks1; x1 += ks2 + 4u;
    TF_R4(13, 15, 26, 6)  x0 += ks2; x1 += ks0 + 5u;
#undef TF_R4
    o0 = x0; o1 = x1;
}

// float -> bf16 (round-to-nearest-even), bit pattern in a short
__device__ static inline short f2bf(float f) {
    uint32_t u = __float_as_uint(f);
    uint32_t r = (u + 0x7FFFu + ((u >> 16) & 1u)) >> 16;
    return (short)r;
}

// ---------------- Prep (fused): W1T, W2B, W2T, Zb0, dv=0 ------------------
// Flat index ranges; outputs coalesced, strided inputs absorbed by L2
// (W1/W2 are 1 MB each).
__global__ __launch_bounds__(256) void k_prep(
    const float* __restrict__ x,  const float* __restrict__ W1,
    const float* __restrict__ W2, short* __restrict__ W1T,
    short* __restrict__ W2B, short* __restrict__ W2T,
    short* __restrict__ zb, float* __restrict__ dv)
{
    const int idx = blockIdx.x * 256 + threadIdx.x;
    if (idx < 262144) {                       // W1T[n][d] = bf16(W1[d][n])
        const int n = idx >> 8, d = idx & 255;
        W1T[idx] = f2bf(W1[d * DIMH + n]);
    } else if (idx < 524288) {                // W2B = bf16(W2) row-major
        const int i = idx - 262144;
        W2B[i] = f2bf(W2[i]);
    } else if (idx < 786432) {                // W2T[d][k] = bf16(W2[k][d])
        const int i = idx - 524288;
        const int d = i >> 10, k = i & 1023;
        W2T[i] = f2bf(W2[k * DIMD + d]);
    } else if (idx < 1835008) {               // zb0 = bf16(x)
        const int i = idx - 786432;
        zb[i] = f2bf(x[i]);
    } else if (idx < 1851392) {               // dv = 0 (4*4096 floats)
        dv[idx - 1835008] = 0.0f;
    }
}

// ---------------- E-gen (all 4 stages): pack Rademacher bits --------------
// bit[j] = (y0^y1)&1 of tf(k2_s, (0, j)), j flat over (10, 4096, 256).
// Word w holds elements j = w*64 + lane (ballot bit i = lane i).
__global__ __launch_bounds__(256) void k_egen4(
    uint64_t* __restrict__ Ep, Keys4 keys)
{
    const int s = blockIdx.y;
    const uint32_t j = blockIdx.x * 256 + threadIdx.x;
    uint32_t y0, y1;
    tf2x32(keys.a[s], keys.b[s], 0u, j, y0, y1);
    uint64_t mask = __ballot(((y0 ^ y1) & 1u) != 0u);
    if ((threadIdx.x & 63) == 0)
        Ep[(size_t)s * NEPW + (j >> 6)] = mask;
}

// ---------------- Fused K1+K3: h-tile + Hutchinson probes -----------------
// Grid (16 n-tiles, 64 batch-tiles) = 1024 blocks. 256 thr = 4 waves; wave
// owns one 16-wide n-subtile: n = nt*64 + wave*16 + col.
// Phase 1 (h): C = Zb(rows b0..63) @ W1T(cols n)^T; tanh epilogue; writes
//   hb (for k_fz2) and keeps s = 1-h^2 in registers — the MFMA C-layout of
//   h is IDENTICAL to the sreg layout the probe loop needs.
// Phase 2 (probes): per probe expand 2 KB packed bits -> LDS E tile, then
//   u = E@W1T^T, v = E@W2B^T via MFMA; rowacc += u*s*v.
// Bank-conflict fix: expansion word remap row = t&63 (lane), cg = t>>6
// (wave) -> store banks (4*lane + 4i) mod 32 = 2-way only (free, m136).
// W2B frags loaded after the h-phase to cap the VGPR peak (no
// min-waves launch_bounds arg: R4/R5 showed it forces spill).
__global__ __launch_bounds__(256) void k_pre_div(
    const short* __restrict__ Zb, const short* __restrict__ W1T,
    const short* __restrict__ W2B, const float* __restrict__ W1,
    const float* __restrict__ b1, float tval,
    const uint64_t* __restrict__ Ep, short* __restrict__ h_bf,
    float* __restrict__ divacc)
{
    __shared__ short E[64 * EPAD];
    const int t = threadIdx.x;
    const int nt = blockIdx.x;         // fastest-varying: blocks share Zb/Ep rows
    const int b0 = blockIdx.y * 64;
    const int wave = t >> 6, lane = t & 63;
    const int col = lane & 15, kq = lane >> 4;
    const int n = nt * 64 + wave * 16 + col;

    // W1T B-fragments (used by h-phase AND u-MFMA)
    short8 bufr[8];
#pragma unroll
    for (int ks = 0; ks < 8; ++ks)
        bufr[ks] = *(const short8*)&W1T[n * DIMD + ks * 32 + kq * 8];

    // ---- Phase 1: h = tanh(Zb @ W1T^T + t*W1[256] + b1) ----
    float sreg[4][4];
    const float add = tval * W1[DIMD * DIMH + n] + b1[n];
#pragma unroll
    for (int ms = 0; ms < 4; ++ms) {
        float4v acc = {0.f, 0.f, 0.f, 0.f};
#pragma unroll
        for (int ks = 0; ks < 8; ++ks) {
            short8 af = *(const short8*)&Zb[(b0 + ms * 16 + col) * DIMD + ks * 32 + kq * 8];
            acc = __builtin_amdgcn_mfma_f32_16x16x32_bf16(af, bufr[ks], acc, 0, 0, 0);
        }
        // C layout: col = lane&15, row = kq*4 + r (verified m89/m91)
#pragma unroll
        for (int r = 0; r < 4; ++r) {
            float hv = tanhf(acc[r] + add);
            h_bf[(b0 + ms * 16 + kq * 4 + r) * DIMH + n] = f2bf(hv);
            sreg[ms][r] = 1.0f - hv * hv;
        }
    }

    // W2B B-fragments (v-MFMA), loaded now to keep h-phase VGPR peak low
    short8 bvfr[8];
#pragma unroll
    for (int ks = 0; ks < 8; ++ks)
        bvfr[ks] = *(const short8*)&W2B[n * DIMD + ks * 32 + kq * 8];

    float rowacc[4][4];
#pragma unroll
    for (int a = 0; a < 4; ++a)
#pragma unroll
        for (int r = 0; r < 4; ++r) rowacc[a][r] = 0.0f;

    // ---- Phase 2: 10 probes ----
    // thread t expands word (row = t&63, colgroup = t>>6)
    const int erow = t & 63, ecg = t >> 6;
    short* const edst = &E[erow * EPAD + ecg * 64];
    const uint64_t* const esrc = Ep + (size_t)b0 * 4 + erow * 4 + ecg;

#pragma unroll 1
    for (int probe = 0; probe < 10; ++probe) {
        __syncthreads();   // previous probe's readers done before overwrite
        uint64_t w = esrc[(size_t)probe * BATCH * 4];
#pragma unroll
        for (int i = 0; i < 8; ++i) {
            short8 val;
#pragma unroll
            for (int k = 0; k < 8; ++k)
                val[k] = ((w >> (i * 8 + k)) & 1ull) ? (short)0x3F80 : (short)0xBF80u;
            *(short8*)&edst[i * 8] = val;
        }
        __syncthreads();

#pragma unroll
        for (int ms = 0; ms < 4; ++ms) {
            const short* arow = &E[(ms * 16 + col) * EPAD + kq * 8];
            float4v u = {0.f, 0.f, 0.f, 0.f}, v = {0.f, 0.f, 0.f, 0.f};
#pragma unroll
            for (int ks = 0; ks < 8; ++ks) {
                short8 af = *(const short8*)&arow[ks * 32];
                u = __builtin_amdgcn_mfma_f32_16x16x32_bf16(af, bufr[ks], u, 0, 0, 0);
                v = __builtin_amdgcn_mfma_f32_16x16x32_bf16(af, bvfr[ks], v, 0, 0, 0);
            }
#pragma unroll
            for (int r = 0; r < 4; ++r)
                rowacc[ms][r] += u[r] * sreg[ms][r] * v[r];
        }
    }

#pragma unroll
    for (int ms = 0; ms < 4; ++ms) {
#pragma unroll
        for (int r = 0; r < 4; ++r) {
            float p = rowacc[ms][r];
            p += __shfl_xor(p, 1, 64);
            p += __shfl_xor(p, 2, 64);
            p += __shfl_xor(p, 4, 64);
            p += __shfl_xor(p, 8, 64);
            rowacc[ms][r] = p;
        }
    }
    if (col == 0) {
#pragma unroll
        for (int ms = 0; ms < 4; ++ms)
#pragma unroll
            for (int r = 0; r < 4; ++r)
                atomicAdd(&divacc[b0 + ms * 16 + kq * 4 + r], rowacc[ms][r] * 0.1f);
    }
}

// ---------------- K2: fz = Hb @ W2 + b2 (fp32 out); fuse Zb_next ----------
// MFMA 16x16x32, K=1024 pipelined. Block 256 thr = 4 waves; wave = 16 rows
// x 64 cols (waves tile N=256). Grid = 4096/16 = 256.
__global__ __launch_bounds__(256) void k_fz2(
    const short* __restrict__ Hb, const short* __restrict__ W2T,
    const float* __restrict__ b2, const float* __restrict__ x,
    float* __restrict__ fz, float cnext, int write_zb, short* __restrict__ zb)
{
    const int t = threadIdx.x;
    const int wave = t >> 6, lane = t & 63;
    const int col = lane & 15, kq = lane >> 4;
    const int m0 = blockIdx.x * 16;
    const int n0 = wave * 64;

    float4v acc[4];
#pragma unroll
    for (int ns = 0; ns < 4; ++ns) acc[ns] = (float4v){0.f, 0.f, 0.f, 0.f};

    const short* ap = &Hb[(m0 + col) * DIMH + kq * 8];
    short8 a_cur = *(const short8*)ap;
    short8 b_cur[4];
#pragma unroll
    for (int ns = 0; ns < 4; ++ns)
        b_cur[ns] = *(const short8*)&W2T[(n0 + ns * 16 + col) * DIMH + kq * 8];

    for (int ks = 0; ks < 31; ++ks) {
        short8 a_nxt = *(const short8*)&ap[(ks + 1) * 32];
        short8 b_nxt[4];
#pragma unroll
        for (int ns = 0; ns < 4; ++ns)
            b_nxt[ns] = *(const short8*)&W2T[(n0 + ns * 16 + col) * DIMH + (ks + 1) * 32 + kq * 8];
#pragma unroll
        for (int ns = 0; ns < 4; ++ns)
            acc[ns] = __builtin_amdgcn_mfma_f32_16x16x32_bf16(a_cur, b_cur[ns], acc[ns], 0, 0, 0);
        a_cur = a_nxt;
#pragma unroll
        for (int ns = 0; ns < 4; ++ns) b_cur[ns] = b_nxt[ns];
    }
#pragma unroll
    for (int ns = 0; ns < 4; ++ns)
        acc[ns] = __builtin_amdgcn_mfma_f32_16x16x32_bf16(a_cur, b_cur[ns], acc[ns], 0, 0, 0);

#pragma unroll
    for (int ns = 0; ns < 4; ++ns) {
        const int n = n0 + ns * 16 + col;
        const float bias = b2[n];
#pragma unroll
        for (int r = 0; r < 4; ++r) {
            const int m = m0 + kq * 4 + r;
            const float val = acc[ns][r] + bias;
            fz[m * DIMD + n] = val;
            if (write_zb)
                zb[m * DIMD + n] = f2bf(x[m * DIMD + n] + cnext * val);
        }
    }
}

// ---------------- K4: RK4 combine + output --------------------------------
__global__ __launch_bounds__(256) void k_out(
    const float* __restrict__ x, const float* __restrict__ fz,
    const float* __restrict__ divacc, float* __restrict__ out)
{
    const int idx = blockIdx.x * 256 + threadIdx.x;
    const int TOT = BATCH * (DIMD + 1);
    if (idx >= TOT) return;
    const int b = idx / (DIMD + 1);
    const int c = idx - b * (DIMD + 1);
    const float sixth = 1.0f / 6.0f;
    if (c < DIMD) {
        float xv = x[b * DIMD + c];
        int o = b * DIMD + c;
        float f1 = fz[o];
        float f2 = fz[BATCH * DIMD + o];
        float f3 = fz[2 * BATCH * DIMD + o];
        float f4 = fz[3 * BATCH * DIMD + o];
        out[idx] = xv;
        out[TOT + idx] = xv + (f1 + 2.0f * f2 + 2.0f * f3 + f4) * sixth;
    } else {
        float d1 = divacc[b];
        float d2 = divacc[BATCH + b];
        float d3 = divacc[2 * BATCH + b];
        float d4 = divacc[3 * BATCH + b];
        out[idx] = 0.0f;
        out[TOT + idx] = -(d1 + 2.0f * d2 + 2.0f * d3 + d4) * sixth;
    }
}

// ---------------- launch ---------------------------------------------------
extern "C" void kernel_launch(void* const* d_in, const int* in_sizes, int n_in,
                              void* d_out, int out_size, void* d_ws, size_t ws_size,
                              hipStream_t stream) {
    const float* x  = (const float*)d_in[0];
    const float* W1 = (const float*)d_in[1];
    const float* b1 = (const float*)d_in[2];
    const float* W2 = (const float*)d_in[3];
    const float* b2 = (const float*)d_in[4];
    float* out = (float*)d_out;

    char* ws = (char*)d_ws;
    short* hb    = (short*)(ws);                   // 8 MiB
    float* fz    = (float*)(ws + 8388608);         // 16 MiB
    short* zb    = (short*)(ws + 25165824);        // 2 MiB
    short* w1t   = (short*)(ws + 27262976);        // 512 KiB
    short* w2b   = (short*)(ws + 27787264);        // 512 KiB
    short* w2t   = (short*)(ws + 28311552);        // 512 KiB
    float* dv    = (float*)(ws + 28835840);        // 64 KiB
    uint64_t* ep = (uint64_t*)(ws + 28901376);     // 4*10*4096*256/8 = 5.25 MiB

    // Host-side threefry key derivation (partitionable semantics):
    //   fk_i = tf((0,42),(0,i));  k2_i = tf(fk_i,(0,1))
    Keys4 keys;
    for (uint32_t i = 0; i < 4; ++i) {
        uint32_t f0, f1, g0, g1;
        tf2x32(0u, 42u, 0u, i, f0, f1);
        tf2x32(f0, f1, 0u, 1u, g0, g1);
        keys.a[i] = g0;
        keys.b[i] = g1;
    }

    k_prep<<<7232, 256, 0, stream>>>(x, W1, W2, w1t, w2b, w2t, zb, dv);
    k_egen4<<<dim3(40960, 4), 256, 0, stream>>>(ep, keys);

    const float tvals[4] = {0.0f, 0.5f, 0.5f, 1.0f};
    const float cnext[4] = {0.5f, 0.5f, 1.0f, 0.0f};  // Zb_{s+1} = x + cnext*fz_s
    for (int s = 0; s < 4; ++s) {
        k_pre_div<<<dim3(16, 64), 256, 0, stream>>>(
            zb, w1t, w2b, W1, b1, tvals[s], ep + (size_t)s * NEPW,
            hb, dv + (size_t)s * BATCH);
        k_fz2<<<256, 256, 0, stream>>>(hb, w2t, b2, x,
                                       fz + (size_t)s * BATCH * DIMD,
                                       cnext[s], (s < 3) ? 1 : 0, zb);
    }
    int tot = BATCH * (DIMD + 1);
    k_out<<<(tot + 255) / 256, 256, 0, stream>>>(x, fz, dv, out);
}